// Round 5
// baseline (300.884 us; speedup 1.0000x reference)
//
#include <hip/hip_runtime.h>

// ---------------------------------------------------------------------------
// MultiHeadAttention with clipped relative-position embeddings (q/k/v-side).
// B=4, L=1024, D=1024, N=16, H=64, E=64 (127 distinct distances).
//
// Pipeline:
//   0. convert_kernel : fp32->bf16 x; weights -> k-contiguous B^T layouts
//   1. gemm<0>        : QKV [4096,1024]@[1024,3072]; q/k [B,N,L,H], v ->
//                       v_t [B,N,H,L] (transposed in scatter epilogue).
//                       m97 staging: global_load_lds dwordx4, linear LDS.
//   2. gemm<1>        : k_proj = k @ ke^T (+ kp_edge cols 0/126)
//   3. attn_kernel    : ZERO-BARRIER j-loop. K/V^T fragments read straight
//                       from global (L2; XCD-grouped swizzle). Only Ps and qp
//                       live in LDS (wave-private rows). Phase-split j-loop:
//                       far tiles = rank-1 bias + rowsum; near tiles = bias
//                       gather + injective diagonal pe histogram in registers.
//                       4 blocks/CU resident (grid==capacity, no tail).
//   4. gemm<2>        : attn_out [4096,1024] @ w_o^T -> d_out fp32
// ---------------------------------------------------------------------------

typedef __bf16 bf16x8 __attribute__((ext_vector_type(8)));
typedef float f32x4 __attribute__((ext_vector_type(4)));
typedef unsigned int u32x4 __attribute__((ext_vector_type(4)));

__device__ __forceinline__ unsigned short f2bf(float f) {
    unsigned int u = __builtin_bit_cast(unsigned int, f);
    u += 0x7fffu + ((u >> 16) & 1u);          // RNE
    return (unsigned short)(u >> 16);
}
__device__ __forceinline__ float bf2f(unsigned short s) {
    unsigned int u = ((unsigned int)s) << 16;
    return __builtin_bit_cast(float, u);
}

// async global->LDS, 16 bytes per lane; LDS dest must be wave-uniform base
__device__ __forceinline__ void gl2lds16(const unsigned short* g, unsigned short* l) {
    __builtin_amdgcn_global_load_lds(
        (const __attribute__((address_space(1))) unsigned int*)g,
        (__attribute__((address_space(3))) unsigned int*)l, 16, 0, 0);
}

// ---------------------------------------------------------------------------
// Convert / relayout kernel.
// ---------------------------------------------------------------------------
__global__ void convert_kernel(const float* __restrict__ x,
                               const float* __restrict__ wq,
                               const float* __restrict__ wk,
                               const float* __restrict__ wv,
                               const float* __restrict__ wo,
                               const float* __restrict__ qe,
                               const float* __restrict__ ke,
                               unsigned short* __restrict__ x_bf,
                               unsigned short* __restrict__ wqkv_bt,
                               unsigned short* __restrict__ wo_bt,
                               unsigned short* __restrict__ qe_bf,
                               unsigned short* __restrict__ ke_bf)
{
    const size_t R0 = 4u * 1024 * 1024;
    const size_t R1 = R0 + 3u * 1024 * 1024;
    const size_t R2 = R1 + 1024u * 1024;
    const size_t R3 = R2 + 8192;
    const size_t R4 = R3 + 8192;
    size_t stride = (size_t)gridDim.x * blockDim.x;
    for (size_t i = (size_t)blockIdx.x * blockDim.x + threadIdx.x; i < R4; i += stride) {
        if (i < R0) {
            x_bf[i] = f2bf(x[i]);
        } else if (i < R1) {
            size_t j = i - R0;
            int which = (int)(j >> 20);
            int rem = (int)(j & 0xFFFFF);
            int n = rem >> 16, d = (rem >> 6) & 1023, h = rem & 63;
            const float* w = which == 0 ? wq : which == 1 ? wk : wv;
            wqkv_bt[(size_t)(which * 1024 + n * 64 + h) * 1024 + d] = f2bf(w[rem]);
        } else if (i < R2) {
            int rem = (int)(i - R1);
            int n = rem >> 16, h = (rem >> 10) & 63, m = rem & 1023;
            wo_bt[(size_t)m * 1024 + n * 64 + h] = f2bf(wo[rem]);
        } else if (i < R3) {
            int idx = (int)(i - R2);
            int e = idx >> 6;
            qe_bf[idx] = (e < 127) ? f2bf(qe[idx]) : 0;
        } else {
            int idx = (int)(i - R3);
            int e = idx >> 6;
            ke_bf[idx] = (e < 127) ? f2bf(ke[idx]) : 0;
        }
    }
}

// ---------------------------------------------------------------------------
// 128x128-tile bf16 GEMM, C = A @ Bt^T, m97 staging (global_load_lds x16B,
// linear [128][64] LDS). All M and Bt row counts are multiples of 128 (the
// embed table is padded to 128 rows with zeros) -> no bounds guards.
// MODE 0: scatter -> q/k [B,N,L,H]; v transposed [B,N,H,L]
// MODE 1: bf16 row-major C0; C1 != null: cols 0/126 -> kp_edge[2][65536]
// MODE 2: fp32 row-major C0
// ---------------------------------------------------------------------------
template<int MODE>
__global__ __launch_bounds__(256) void gemm_bt_kernel(
    const unsigned short* __restrict__ A,
    const unsigned short* __restrict__ Bt,
    int K, int lda, int ldb,
    void* __restrict__ C0, void* __restrict__ C1, void* __restrict__ C2,
    int ldc)
{
    __shared__ unsigned short As[128 * 64];
    __shared__ unsigned short Bs[128 * 64];
    const int m0 = blockIdx.y * 128;
    const int n0 = blockIdx.x * 128;
    const int tid = threadIdx.x;
    const int lane = tid & 63;
    const int w = tid >> 6;
    const int wr = w >> 1, wc = w & 1;
    const int g = lane >> 4, c16 = lane & 15;

    f32x4 acc[4][4];
#pragma unroll
    for (int i = 0; i < 4; ++i)
#pragma unroll
        for (int j = 0; j < 4; ++j) acc[i][j] = f32x4{0.f, 0.f, 0.f, 0.f};

    for (int kt = 0; kt < K; kt += 64) {
#pragma unroll
        for (int c = 0; c < 4; ++c) {
            int chunk = c * 256 + tid;           // 1024 chunks of 16B
            int row = chunk >> 3, col = (chunk & 7) * 8;
            unsigned short* ldsA = &As[(c * 256 + w * 64) * 8];   // wave-uniform
            unsigned short* ldsB = &Bs[(c * 256 + w * 64) * 8];
            gl2lds16(A  + (size_t)(m0 + row) * lda + kt + col, ldsA);
            gl2lds16(Bt + (size_t)(n0 + row) * ldb + kt + col, ldsB);
        }
        __syncthreads();
#pragma unroll
        for (int ks = 0; ks < 2; ++ks) {
            bf16x8 af[4], bfr[4];
#pragma unroll
            for (int mi = 0; mi < 4; ++mi)
                af[mi] = __builtin_bit_cast(bf16x8,
                    *reinterpret_cast<const u32x4*>(&As[(wr * 64 + mi * 16 + c16) * 64 + ks * 32 + g * 8]));
#pragma unroll
            for (int ni = 0; ni < 4; ++ni)
                bfr[ni] = __builtin_bit_cast(bf16x8,
                    *reinterpret_cast<const u32x4*>(&Bs[(wc * 64 + ni * 16 + c16) * 64 + ks * 32 + g * 8]));
#pragma unroll
            for (int mi = 0; mi < 4; ++mi)
#pragma unroll
                for (int ni = 0; ni < 4; ++ni)
                    acc[mi][ni] = __builtin_amdgcn_mfma_f32_16x16x32_bf16(af[mi], bfr[ni], acc[mi][ni], 0, 0, 0);
        }
        __syncthreads();
    }

#pragma unroll
    for (int mi = 0; mi < 4; ++mi) {
#pragma unroll
        for (int ni = 0; ni < 4; ++ni) {
#pragma unroll
            for (int r = 0; r < 4; ++r) {
                int m = m0 + wr * 64 + mi * 16 + g * 4 + r;
                int c = n0 + wc * 64 + ni * 16 + c16;
                float v = acc[mi][ni][r];
                if (MODE == 0) {
                    int b = m >> 10, l = m & 1023;
                    int which = c >> 10, n = (c >> 6) & 15, h = c & 63;
                    if (which == 2) {
                        ((unsigned short*)C2)[(((size_t)b * 16 + n) * 64 + h) * 1024 + l] = f2bf(v);
                    } else {
                        unsigned short* dst = (unsigned short*)(which == 0 ? C0 : C1);
                        dst[(((size_t)b * 16 + n) * 1024 + l) * 64 + h] = f2bf(v);
                    }
                } else if (MODE == 1) {
                    ((unsigned short*)C0)[(size_t)m * ldc + c] = f2bf(v);
                    if (C1 && (c == 0 || c == 126))
                        ((unsigned short*)C1)[(size_t)(c ? 65536 : 0) + m] = f2bf(v);
                } else {
                    ((float*)C0)[(size_t)m * ldc + c] = v;
                }
            }
        }
    }
}

// ---------------------------------------------------------------------------
// Fused attention. 1D grid of 1024; id&63 = (b,n) group (same XCD for all 16
// i-tiles of a group under mod-8 round-robin), id>>6 = i-tile.
// LDS main loop : Ps [64][72] @0 (9216B), qp [64][128] @9216 (16384B)
// LDS end overlay: veT [64][136] @0, peB [64][136] @17408, lrow @34816
// No barriers in the j-loop (all LDS rows wave-private); 2 barriers total.
// ---------------------------------------------------------------------------
#define ATTN_LDS_BYTES 35072

__global__ __launch_bounds__(256, 4) void attn_kernel(
    const unsigned short* __restrict__ q_buf,   // [B,N,L,H] bf16
    const unsigned short* __restrict__ k_buf,   // [B,N,L,H] bf16
    const unsigned short* __restrict__ v_t,     // [B,N,H,L] bf16
    const unsigned short* __restrict__ qe_g,    // [128,64] bf16 (row 127 = 0)
    const unsigned short* __restrict__ k_proj,  // [B,N,L,128] bf16
    const unsigned short* __restrict__ kp_edge, // [2][65536] bf16 (e=0,126)
    const float* __restrict__ v_emb,            // [127,64] fp32
    const int* __restrict__ mask,               // [B,1024]
    unsigned short* __restrict__ attn_out)      // [B,L,N,H] bf16
{
    extern __shared__ char smem[];
    unsigned short* Ps = (unsigned short*)smem;            // [64][72]
    unsigned short* qp = (unsigned short*)(smem + 9216);   // [64][128]
    unsigned short* veT = (unsigned short*)smem;           // [64][136] overlay
    unsigned short* peB = (unsigned short*)(smem + 17408); // [64][136] overlay
    float* lrow = (float*)(smem + 34816);                  // [64]

    const int id = blockIdx.x;
    const int bn = id & 63;                  // = b*16 + n
    const int it_ = id >> 6;
    const int b = bn >> 4;
    const int i0 = it_ * 64;
    const int tid = threadIdx.x;
    const int lane = tid & 63;
    const int w = tid >> 6;
    const int g = lane >> 4, c16 = lane & 15;
    const int il = tid >> 2;                 // histogram row (wave-private)
    const int part = tid & 3;                // bins [part*32, part*32+32)

    // Q fragments for this wave's 16 rows (A-row = c16), k-slot = ks*32+8g+e
    bf16x8 qf[2];
    {
        const unsigned short* qrow = q_buf + ((size_t)bn * 1024 + i0 + w * 16 + c16) * 64;
        qf[0] = __builtin_bit_cast(bf16x8, *reinterpret_cast<const u32x4*>(qrow + g * 8));
        qf[1] = __builtin_bit_cast(bf16x8, *reinterpret_cast<const u32x4*>(qrow + 32 + g * 8));
    }

    // ---- qp = q_tile @ qe^T in-block (wave-private rows) ----
    {
        f32x4 qacc[8];
#pragma unroll
        for (int nf = 0; nf < 8; ++nf) qacc[nf] = f32x4{0.f, 0.f, 0.f, 0.f};
#pragma unroll
        for (int ks = 0; ks < 2; ++ks) {
#pragma unroll
            for (int nf = 0; nf < 8; ++nf) {
                bf16x8 bfr = __builtin_bit_cast(bf16x8,
                    *reinterpret_cast<const u32x4*>(qe_g + (nf * 16 + c16) * 64 + ks * 32 + g * 8));
                qacc[nf] = __builtin_amdgcn_mfma_f32_16x16x32_bf16(qf[ks], bfr, qacc[nf], 0, 0, 0);
            }
        }
#pragma unroll
        for (int nf = 0; nf < 8; ++nf)
#pragma unroll
            for (int r = 0; r < 4; ++r)
                qp[(w * 16 + g * 4 + r) * 128 + nf * 16 + c16] = f2bf(qacc[nf][r]);
    }
    // loop-invariant far-tile qp columns (wave-private LDS)
    f32x4 qp0v, qp126v;
#pragma unroll
    for (int r = 0; r < 4; ++r) {
        qp0v[r]   = 0.125f * bf2f(qp[(w * 16 + g * 4 + r) * 128 + 0]);
        qp126v[r] = 0.125f * bf2f(qp[(w * 16 + g * 4 + r) * 128 + 126]);
    }

    float lreg = 0.f, acc0 = 0.f, acc126 = 0.f;
    f32x4 accO[4];
#pragma unroll
    for (int i = 0; i < 4; ++i) accO[i] = f32x4{0.f, 0.f, 0.f, 0.f};

    // O += P @ V  (P rows wave-private; V^T fragments straight from global)
    auto pv = [&](int j0) {
#pragma unroll
        for (int ks = 0; ks < 2; ++ks) {
            bf16x8 pf = __builtin_bit_cast(bf16x8,
                *reinterpret_cast<const u32x4*>(&Ps[(w * 16 + c16) * 72 + ks * 32 + g * 8]));
#pragma unroll
            for (int nf2 = 0; nf2 < 4; ++nf2) {
                bf16x8 vf = __builtin_bit_cast(bf16x8,
                    *reinterpret_cast<const u32x4*>(v_t + ((size_t)bn * 64 + nf2 * 16 + c16) * 1024 + j0 + ks * 32 + g * 8));
                accO[nf2] = __builtin_amdgcn_mfma_f32_16x16x32_bf16(pf, vf, accO[nf2], 0, 0, 0);
            }
        }
    };
    // S = Q K^T for one 64-col tile (K fragments straight from global)
    auto qkt = [&](int j0, f32x4* sacc) {
        bf16x8 kf[8];
#pragma unroll
        for (int ks = 0; ks < 2; ++ks)
#pragma unroll
            for (int nf = 0; nf < 4; ++nf)
                kf[ks * 4 + nf] = __builtin_bit_cast(bf16x8,
                    *reinterpret_cast<const u32x4*>(k_buf + ((size_t)bn * 1024 + j0 + nf * 16 + c16) * 64 + ks * 32 + g * 8));
#pragma unroll
        for (int ks = 0; ks < 2; ++ks)
#pragma unroll
            for (int nf = 0; nf < 4; ++nf)
                sacc[nf] = __builtin_amdgcn_mfma_f32_16x16x32_bf16(qf[ks], kf[ks * 4 + nf], sacc[nf], 0, 0, 0);
    };
    // row sum of this thread's 16-col slice of its row, 4-lane reduced
    auto rowsum = [&]() -> float {
        bf16x8 s0 = __builtin_bit_cast(bf16x8,
            *reinterpret_cast<const u32x4*>(&Ps[il * 72 + part * 16]));
        bf16x8 s1 = __builtin_bit_cast(bf16x8,
            *reinterpret_cast<const u32x4*>(&Ps[il * 72 + part * 16 + 8]));
        float rs = 0.f;
#pragma unroll
        for (int m = 0; m < 8; ++m) rs += (float)s0[m] + (float)s1[m];
        rs += __shfl_xor(rs, 1);
        rs += __shfl_xor(rs, 2);
        return rs;
    };

    // far tile: clipped e is constant -> rank-1 bias, histogram = rowsum
    auto far_tile = [&](int jt, const unsigned short* kedge_plane, f32x4 qpc, float& eacc) {
        const int j0 = jt * 64;
        float mfl[4], kpe[4];
#pragma unroll
        for (int nf = 0; nf < 4; ++nf) {
            int j_l = nf * 16 + c16;
            mfl[nf] = mask[b * 1024 + j0 + j_l] ? 1.f : 0.f;
            kpe[nf] = 0.125f * bf2f(kedge_plane[(size_t)bn * 1024 + j0 + j_l]);
        }
        f32x4 sacc[4];
#pragma unroll
        for (int nf = 0; nf < 4; ++nf) sacc[nf] = f32x4{0.f, 0.f, 0.f, 0.f};
        qkt(j0, sacc);
#pragma unroll
        for (int nf = 0; nf < 4; ++nf) {
#pragma unroll
            for (int r = 0; r < 4; ++r) {
                float s = sacc[nf][r] * 0.125f + kpe[nf] + qpc[r];
                float p = (mfl[nf] > 0.f) ? __expf(s) : 0.f;
                Ps[(w * 16 + g * 4 + r) * 72 + nf * 16 + c16] = f2bf(p);
            }
        }
        pv(j0);
        float rs = rowsum();
        lreg += rs;
        eacc += rs;
    };

    const int jb0 = it_ > 0 ? it_ - 1 : 0;
    const int jb1 = it_ < 15 ? it_ + 1 : 15;

    // ---- phase A: far-low (dt >= 2, e = 126) ----
    for (int jt = 0; jt < jb0; ++jt) far_tile(jt, kp_edge + 65536, qp126v, acc126);

    // ---- phase B: near tiles (|dt| <= 1), full bias gather + pe bins ----
    float peR[32];
#pragma unroll
    for (int k = 0; k < 32; ++k) peR[k] = 0.f;
    for (int jt = jb0; jt <= jb1; ++jt) {
        const int j0 = jt * 64;
        const int dt = it_ - jt;
        float mfl[4];
#pragma unroll
        for (int nf = 0; nf < 4; ++nf)
            mfl[nf] = mask[b * 1024 + j0 + nf * 16 + c16] ? 1.f : 0.f;
        f32x4 sacc[4];
#pragma unroll
        for (int nf = 0; nf < 4; ++nf) sacc[nf] = f32x4{0.f, 0.f, 0.f, 0.f};
        qkt(j0, sacc);
        const unsigned short* kpg = k_proj + ((size_t)bn * 1024 + j0) * 128;
#pragma unroll
        for (int nf = 0; nf < 4; ++nf) {
            int j_l = nf * 16 + c16;
#pragma unroll
            for (int r = 0; r < 4; ++r) {
                int i_l = w * 16 + g * 4 + r;
                int e = i_l - j_l + dt * 64 + 63;
                e = e < 0 ? 0 : (e > 126 ? 126 : e);
                float s = sacc[nf][r] + bf2f(kpg[j_l * 128 + e]) + bf2f(qp[i_l * 128 + e]);
                s *= 0.125f;
                float p = (mfl[nf] > 0.f) ? __expf(s) : 0.f;
                Ps[i_l * 72 + j_l] = f2bf(p);
            }
        }
        pv(j0);
        // histogram: rowsum + clipped bins (predicated) + injective diagonal
        {
            bf16x8 s0 = __builtin_bit_cast(bf16x8,
                *reinterpret_cast<const u32x4*>(&Ps[il * 72 + part * 16]));
            bf16x8 s1 = __builtin_bit_cast(bf16x8,
                *reinterpret_cast<const u32x4*>(&Ps[il * 72 + part * 16 + 8]));
            float v[16];
#pragma unroll
            for (int m = 0; m < 8; ++m) { v[m] = (float)s0[m]; v[8 + m] = (float)s1[m]; }
            float rs = 0.f;
#pragma unroll
            for (int m = 0; m < 16; ++m) rs += v[m];
            rs += __shfl_xor(rs, 1);
            rs += __shfl_xor(rs, 2);
            lreg += rs;

            const int base = il + dt * 64 + 63;   // jl for bin e is base - e
            float b0 = 0.f, b126 = 0.f;
#pragma unroll
            for (int m = 0; m < 16; ++m) {
                int jl = part * 16 + m;
                if (jl >= base) b0 += v[m];
                if (jl <= base - 126) b126 += v[m];
            }
            b0 += __shfl_xor(b0, 1);     b0 += __shfl_xor(b0, 2);
            b126 += __shfl_xor(b126, 1); b126 += __shfl_xor(b126, 2);
            if (part == 0) peR[0] += b0;
            if (part == 3) peR[30] += b126;
#pragma unroll
            for (int k = 0; k < 32; ++k) {
                int e = part * 32 + k;
                int jl = base - e;
                if (e >= 1 && e <= 125 && jl >= 0 && jl < 64)
                    peR[k] += bf2f(Ps[il * 72 + jl]);
            }
        }
    }

    // ---- phase C: far-high (dt <= -2, e = 0) ----
    for (int jt = jb1 + 1; jt < 16; ++jt) far_tile(jt, kp_edge, qp0v, acc0);

    if (part == 0) peR[0] += acc0;
    if (part == 3) peR[30] += acc126;

    // ---- end phase ----
    __syncthreads();                              // Ps/qp reads all done
#pragma unroll
    for (int it = 0; it < 32; ++it) {
        int idx = tid + it * 256;                 // 8192 = 64*128
        int h = idx >> 7, e = idx & 127;
        veT[h * 136 + e] = (e < 127) ? f2bf(v_emb[e * 64 + h]) : 0;
    }
#pragma unroll
    for (int kk = 0; kk < 4; ++kk) {              // pe spill as bf16
        bf16x8 pk;
#pragma unroll
        for (int e2 = 0; e2 < 8; ++e2) pk[e2] = (__bf16)peR[kk * 8 + e2];
        *reinterpret_cast<u32x4*>(&peB[il * 136 + part * 32 + kk * 8]) =
            __builtin_bit_cast(u32x4, pk);
    }
    if (part == 0) lrow[il] = lreg;
    __syncthreads();                              // veT/peB/lrow visible

    // O += pe @ veT   (K = 128; col 127 zero on both sides)
#pragma unroll
    for (int ks = 0; ks < 4; ++ks) {
        bf16x8 pf = __builtin_bit_cast(bf16x8,
            *reinterpret_cast<const u32x4*>(&peB[(w * 16 + c16) * 136 + ks * 32 + g * 8]));
#pragma unroll
        for (int nf2 = 0; nf2 < 4; ++nf2) {
            bf16x8 vf = __builtin_bit_cast(bf16x8,
                *reinterpret_cast<const u32x4*>(&veT[(nf2 * 16 + c16) * 136 + ks * 32 + g * 8]));
            accO[nf2] = __builtin_amdgcn_mfma_f32_16x16x32_bf16(pf, vf, accO[nf2], 0, 0, 0);
        }
    }

    // epilogue: attn_out[b, i, n, h] = O / l
#pragma unroll
    for (int nf2 = 0; nf2 < 4; ++nf2) {
#pragma unroll
        for (int r = 0; r < 4; ++r) {
            int i_l = w * 16 + g * 4 + r;
            int h = nf2 * 16 + c16;
            float vv = accO[nf2][r] / lrow[i_l];
            attn_out[(((size_t)b * 1024 + i0 + i_l) * 16 + (bn & 15)) * 64 + h] = f2bf(vv);
        }
    }
}

// ---------------------------------------------------------------------------
extern "C" void kernel_launch(void* const* d_in, const int* in_sizes, int n_in,
                              void* d_out, int out_size, void* d_ws, size_t ws_size,
                              hipStream_t stream)
{
    const float* x  = (const float*)d_in[0];
    const int* mask = (const int*)d_in[1];
    const float* wq = (const float*)d_in[2];
    const float* wk = (const float*)d_in[3];
    const float* wv = (const float*)d_in[4];
    const float* wo = (const float*)d_in[5];
    const float* qe = (const float*)d_in[6];
    const float* ke = (const float*)d_in[7];
    const float* ve = (const float*)d_in[8];

    char* ws = (char*)d_ws;
    size_t off = 0;
    auto carve = [&](size_t bytes) -> char* {
        char* p = ws + off;
        off += (bytes + 255) & ~(size_t)255;
        return p;
    };
    unsigned short* x_bf    = (unsigned short*)carve(4096ull * 1024 * 2);   //  8 MB
    unsigned short* wqkv_bt = (unsigned short*)carve(3072ull * 1024 * 2);   //  6 MB
    unsigned short* wo_bt   = (unsigned short*)carve(1024ull * 1024 * 2);   //  2 MB
    unsigned short* qe_bf   = (unsigned short*)carve(128ull * 64 * 2);
    unsigned short* ke_bf   = (unsigned short*)carve(128ull * 64 * 2);
    unsigned short* q_buf   = (unsigned short*)carve(65536ull * 64 * 2);    //  8 MB
    unsigned short* k_buf   = (unsigned short*)carve(65536ull * 64 * 2);    //  8 MB
    unsigned short* v_t     = (unsigned short*)carve(65536ull * 64 * 2);    //  8 MB
    unsigned short* k_proj  = (unsigned short*)carve(65536ull * 128 * 2);   // 16 MB
    unsigned short* kp_edge = (unsigned short*)carve(2ull * 65536 * 2);     // 256 KB
    unsigned short* attn_o  = (unsigned short*)carve(4096ull * 1024 * 2);   //  8 MB
    (void)ws_size; (void)in_sizes; (void)n_in; (void)out_size;

    convert_kernel<<<2048, 256, 0, stream>>>(x, wq, wk, wv, wo, qe, ke,
                                             x_bf, wqkv_bt, wo_bt, qe_bf, ke_bf);

    // QKV: [4096,1024] @ [1024,3072]; v written transposed
    gemm_bt_kernel<0><<<dim3(24, 32), 256, 0, stream>>>(
        x_bf, wqkv_bt, 1024, 1024, 1024, q_buf, k_buf, v_t, 0);

    // k_proj: [65536,64] @ [64,128(127)] (+ edge cols)
    gemm_bt_kernel<1><<<dim3(1, 512), 256, 0, stream>>>(
        k_buf, ke_bf, 64, 64, 64, k_proj, kp_edge, nullptr, 128);

    // fused attention (zero-barrier main loop, XCD-grouped 1D swizzle)
    hipFuncSetAttribute((const void*)attn_kernel,
                        hipFuncAttributeMaxDynamicSharedMemorySize, ATTN_LDS_BYTES);
    attn_kernel<<<1024, 256, ATTN_LDS_BYTES, stream>>>(
        q_buf, k_buf, v_t, qe_bf, k_proj, kp_edge, ve, mask, attn_o);

    // output projection: [4096,1024] @ [1024,1024] -> fp32 d_out
    gemm_bt_kernel<2><<<dim3(8, 32), 256, 0, stream>>>(
        attn_o, wo_bt, 1024, 1024, 1024, d_out, nullptr, nullptr, 1024);
}

// Round 7
// 291.983 us; speedup vs baseline: 1.0305x; 1.0305x over previous
//
#include <hip/hip_runtime.h>

// ---------------------------------------------------------------------------
// MultiHeadAttention with clipped relative-position embeddings (q/k/v-side).
// B=4, L=1024, D=1024, N=16, H=64, E=64 (127 distinct distances).
//
// Pipeline:
//   0. convert_kernel : fp32->bf16 x; weights -> k-contiguous B^T layouts;
//                       v_emb -> transposed bf16 [64][128]
//   1. gemm<0>        : QKV [4096,1024]@[1024,3072]; q/k [B,N,L,H], v ->
//                       v_t [B,N,H,L]. m97 staging (global_load_lds x16B).
//   2. gemm<1>        : k_proj = k @ ke^T (+ kp_edge cols 0/126)
//   3. attn_kernel    : shared stride-72 K/V^T LDS tiles staged via T14
//                       async reg-split ONE TILE AHEAD (loads issue at top of
//                       compute, ds_write after barrier). In-block qp; far
//                       tiles rank-1 bias; near tiles gather; register pe
//                       bins; 2 barriers/tile; 3 blocks/CU.
//   4. gemm<2>        : attn_out [4096,1024] @ w_o^T -> d_out fp32
// Round 7 fix: veT end-phase staging was 512 chunks (rows 0..31 only) ->
// rows 32..63 held stale Ks/Vt bits incl. NaN bf16 patterns. Now 1024 chunks.
// ---------------------------------------------------------------------------

typedef __bf16 bf16x8 __attribute__((ext_vector_type(8)));
typedef float f32x4 __attribute__((ext_vector_type(4)));
typedef unsigned int u32x4 __attribute__((ext_vector_type(4)));

__device__ __forceinline__ unsigned short f2bf(float f) {
    unsigned int u = __builtin_bit_cast(unsigned int, f);
    u += 0x7fffu + ((u >> 16) & 1u);          // RNE
    return (unsigned short)(u >> 16);
}
__device__ __forceinline__ float bf2f(unsigned short s) {
    unsigned int u = ((unsigned int)s) << 16;
    return __builtin_bit_cast(float, u);
}

// async global->LDS, 16 bytes per lane; LDS dest must be wave-uniform base
__device__ __forceinline__ void gl2lds16(const unsigned short* g, unsigned short* l) {
    __builtin_amdgcn_global_load_lds(
        (const __attribute__((address_space(1))) unsigned int*)g,
        (__attribute__((address_space(3))) unsigned int*)l, 16, 0, 0);
}

// ---------------------------------------------------------------------------
// Convert / relayout kernel.
// ---------------------------------------------------------------------------
__global__ void convert_kernel(const float* __restrict__ x,
                               const float* __restrict__ wq,
                               const float* __restrict__ wk,
                               const float* __restrict__ wv,
                               const float* __restrict__ wo,
                               const float* __restrict__ qe,
                               const float* __restrict__ ke,
                               const float* __restrict__ ve,
                               unsigned short* __restrict__ x_bf,
                               unsigned short* __restrict__ wqkv_bt,
                               unsigned short* __restrict__ wo_bt,
                               unsigned short* __restrict__ qe_bf,
                               unsigned short* __restrict__ ke_bf,
                               unsigned short* __restrict__ ve_t)
{
    const size_t R0 = 4u * 1024 * 1024;
    const size_t R1 = R0 + 3u * 1024 * 1024;
    const size_t R2 = R1 + 1024u * 1024;
    const size_t R3 = R2 + 8192;
    const size_t R4 = R3 + 8192;
    const size_t R5 = R4 + 8192;
    size_t stride = (size_t)gridDim.x * blockDim.x;
    for (size_t i = (size_t)blockIdx.x * blockDim.x + threadIdx.x; i < R5; i += stride) {
        if (i < R0) {
            x_bf[i] = f2bf(x[i]);
        } else if (i < R1) {
            size_t j = i - R0;
            int which = (int)(j >> 20);
            int rem = (int)(j & 0xFFFFF);
            int n = rem >> 16, d = (rem >> 6) & 1023, h = rem & 63;
            const float* w = which == 0 ? wq : which == 1 ? wk : wv;
            wqkv_bt[(size_t)(which * 1024 + n * 64 + h) * 1024 + d] = f2bf(w[rem]);
        } else if (i < R2) {
            int rem = (int)(i - R1);
            int n = rem >> 16, h = (rem >> 10) & 63, m = rem & 1023;
            wo_bt[(size_t)m * 1024 + n * 64 + h] = f2bf(wo[rem]);
        } else if (i < R3) {
            int idx = (int)(i - R2);
            int e = idx >> 6;
            qe_bf[idx] = (e < 127) ? f2bf(qe[idx]) : 0;
        } else if (i < R4) {
            int idx = (int)(i - R3);
            int e = idx >> 6;
            ke_bf[idx] = (e < 127) ? f2bf(ke[idx]) : 0;
        } else {
            int idx = (int)(i - R4);          // ve transposed: [h=64][e=128]
            int h = idx >> 7, e = idx & 127;
            ve_t[idx] = (e < 127) ? f2bf(ve[e * 64 + h]) : 0;
        }
    }
}

// ---------------------------------------------------------------------------
// 128x128-tile bf16 GEMM, C = A @ Bt^T, m97 staging (global_load_lds x16B,
// linear [128][64] LDS). All row counts multiples of 128 (embed padded).
// MODE 0: scatter -> q/k [B,N,L,H]; v transposed [B,N,H,L]
// MODE 1: bf16 row-major C0; C1 != null: cols 0/126 -> kp_edge[2][65536]
// MODE 2: fp32 row-major C0
// ---------------------------------------------------------------------------
template<int MODE>
__global__ __launch_bounds__(256) void gemm_bt_kernel(
    const unsigned short* __restrict__ A,
    const unsigned short* __restrict__ Bt,
    int K, int lda, int ldb,
    void* __restrict__ C0, void* __restrict__ C1, void* __restrict__ C2,
    int ldc)
{
    __shared__ unsigned short As[128 * 64];
    __shared__ unsigned short Bs[128 * 64];
    const int m0 = blockIdx.y * 128;
    const int n0 = blockIdx.x * 128;
    const int tid = threadIdx.x;
    const int lane = tid & 63;
    const int w = tid >> 6;
    const int wr = w >> 1, wc = w & 1;
    const int g = lane >> 4, c16 = lane & 15;

    f32x4 acc[4][4];
#pragma unroll
    for (int i = 0; i < 4; ++i)
#pragma unroll
        for (int j = 0; j < 4; ++j) acc[i][j] = f32x4{0.f, 0.f, 0.f, 0.f};

    for (int kt = 0; kt < K; kt += 64) {
#pragma unroll
        for (int c = 0; c < 4; ++c) {
            int chunk = c * 256 + tid;           // 1024 chunks of 16B
            int row = chunk >> 3, col = (chunk & 7) * 8;
            unsigned short* ldsA = &As[(c * 256 + w * 64) * 8];   // wave-uniform
            unsigned short* ldsB = &Bs[(c * 256 + w * 64) * 8];
            gl2lds16(A  + (size_t)(m0 + row) * lda + kt + col, ldsA);
            gl2lds16(Bt + (size_t)(n0 + row) * ldb + kt + col, ldsB);
        }
        __syncthreads();
#pragma unroll
        for (int ks = 0; ks < 2; ++ks) {
            bf16x8 af[4], bfr[4];
#pragma unroll
            for (int mi = 0; mi < 4; ++mi)
                af[mi] = __builtin_bit_cast(bf16x8,
                    *reinterpret_cast<const u32x4*>(&As[(wr * 64 + mi * 16 + c16) * 64 + ks * 32 + g * 8]));
#pragma unroll
            for (int ni = 0; ni < 4; ++ni)
                bfr[ni] = __builtin_bit_cast(bf16x8,
                    *reinterpret_cast<const u32x4*>(&Bs[(wc * 64 + ni * 16 + c16) * 64 + ks * 32 + g * 8]));
#pragma unroll
            for (int mi = 0; mi < 4; ++mi)
#pragma unroll
                for (int ni = 0; ni < 4; ++ni)
                    acc[mi][ni] = __builtin_amdgcn_mfma_f32_16x16x32_bf16(af[mi], bfr[ni], acc[mi][ni], 0, 0, 0);
        }
        __syncthreads();
    }

#pragma unroll
    for (int mi = 0; mi < 4; ++mi) {
#pragma unroll
        for (int ni = 0; ni < 4; ++ni) {
#pragma unroll
            for (int r = 0; r < 4; ++r) {
                int m = m0 + wr * 64 + mi * 16 + g * 4 + r;
                int c = n0 + wc * 64 + ni * 16 + c16;
                float v = acc[mi][ni][r];
                if (MODE == 0) {
                    int b = m >> 10, l = m & 1023;
                    int which = c >> 10, n = (c >> 6) & 15, h = c & 63;
                    if (which == 2) {
                        ((unsigned short*)C2)[(((size_t)b * 16 + n) * 64 + h) * 1024 + l] = f2bf(v);
                    } else {
                        unsigned short* dst = (unsigned short*)(which == 0 ? C0 : C1);
                        dst[(((size_t)b * 16 + n) * 1024 + l) * 64 + h] = f2bf(v);
                    }
                } else if (MODE == 1) {
                    ((unsigned short*)C0)[(size_t)m * ldc + c] = f2bf(v);
                    if (C1 && (c == 0 || c == 126))
                        ((unsigned short*)C1)[(size_t)(c ? 65536 : 0) + m] = f2bf(v);
                } else {
                    ((float*)C0)[(size_t)m * ldc + c] = v;
                }
            }
        }
    }
}

// ---------------------------------------------------------------------------
// Fused attention. 1D grid of 1024; id&63 = (b,n) group (XCD-local under
// mod-8 round-robin), id>>6 = i-tile.
// LDS: Ks[64][72]@0, Vt[64][72]@9216, Ps[64][72]@18432, qp[64][128]@27648
//      (total 44032). End overlay: veT[64][136]@0, peB[64][136]@17408,
//      lrow@34816.
// K/V staged via reg-split one tile ahead; 2 barriers/tile.
// ---------------------------------------------------------------------------
#define ATTN_LDS_BYTES 44032

__global__ __launch_bounds__(256, 3) void attn_kernel(
    const unsigned short* __restrict__ q_buf,   // [B,N,L,H] bf16
    const unsigned short* __restrict__ k_buf,   // [B,N,L,H] bf16
    const unsigned short* __restrict__ v_t,     // [B,N,H,L] bf16
    const unsigned short* __restrict__ qe_g,    // [128,64] bf16 (row 127 = 0)
    const unsigned short* __restrict__ k_proj,  // [B,N,L,128] bf16
    const unsigned short* __restrict__ kp_edge, // [2][65536] bf16 (e=0,126)
    const unsigned short* __restrict__ ve_t,    // [64][128] bf16 (col 127 = 0)
    const int* __restrict__ mask,               // [B,1024]
    unsigned short* __restrict__ attn_out)      // [B,L,N,H] bf16
{
    extern __shared__ char smem[];
    unsigned short* Ks = (unsigned short*)smem;            // [64][72]
    unsigned short* Vt = (unsigned short*)(smem + 9216);   // [64][72]
    unsigned short* Ps = (unsigned short*)(smem + 18432);  // [64][72]
    unsigned short* qp = (unsigned short*)(smem + 27648);  // [64][128]
    unsigned short* veT = (unsigned short*)smem;           // [64][136] overlay
    unsigned short* peB = (unsigned short*)(smem + 17408); // [64][136] overlay
    float* lrow = (float*)(smem + 34816);                  // [64]

    const int id = blockIdx.x;
    const int bn = id & 63;                  // = b*16 + n
    const int it_ = id >> 6;
    const int b = bn >> 4;
    const int i0 = it_ * 64;
    const int tid = threadIdx.x;
    const int lane = tid & 63;
    const int w = tid >> 6;
    const int g = lane >> 4, c16 = lane & 15;
    const int il = tid >> 2;                 // histogram row (wave-private)
    const int part = tid & 3;                // bins [part*32, part*32+32)

    // staging geometry: 512 chunks of 16B per 8KB tile, 2 chunks/thread
    const int sr0 = tid >> 3,          sc0 = (tid & 7) * 8;
    const int sr1 = (tid + 256) >> 3,  sc1 = (tid & 7) * 8;
    u32x4 kr0, kr1, vr0, vr1;                // prefetch registers
    auto load_tile = [&](int j0) {
        kr0 = *reinterpret_cast<const u32x4*>(k_buf + ((size_t)bn * 1024 + j0 + sr0) * 64 + sc0);
        kr1 = *reinterpret_cast<const u32x4*>(k_buf + ((size_t)bn * 1024 + j0 + sr1) * 64 + sc1);
        vr0 = *reinterpret_cast<const u32x4*>(v_t + ((size_t)bn * 64 + sr0) * 1024 + j0 + sc0);
        vr1 = *reinterpret_cast<const u32x4*>(v_t + ((size_t)bn * 64 + sr1) * 1024 + j0 + sc1);
    };
    auto write_tile = [&]() {
        *reinterpret_cast<u32x4*>(&Ks[sr0 * 72 + sc0]) = kr0;
        *reinterpret_cast<u32x4*>(&Ks[sr1 * 72 + sc1]) = kr1;
        *reinterpret_cast<u32x4*>(&Vt[sr0 * 72 + sc0]) = vr0;
        *reinterpret_cast<u32x4*>(&Vt[sr1 * 72 + sc1]) = vr1;
    };

    load_tile(0);                            // tile 0 in flight

    // Q fragments for this wave's 16 rows (A-row = c16), k-slot = ks*32+8g+e
    bf16x8 qf[2];
    {
        const unsigned short* qrow = q_buf + ((size_t)bn * 1024 + i0 + w * 16 + c16) * 64;
        qf[0] = __builtin_bit_cast(bf16x8, *reinterpret_cast<const u32x4*>(qrow + g * 8));
        qf[1] = __builtin_bit_cast(bf16x8, *reinterpret_cast<const u32x4*>(qrow + 32 + g * 8));
    }
    // ---- qp = q_tile @ qe^T in-block (overlaps tile-0 loads) ----
    {
        f32x4 qacc[8];
#pragma unroll
        for (int nf = 0; nf < 8; ++nf) qacc[nf] = f32x4{0.f, 0.f, 0.f, 0.f};
#pragma unroll
        for (int ks = 0; ks < 2; ++ks) {
#pragma unroll
            for (int nf = 0; nf < 8; ++nf) {
                bf16x8 bfr = __builtin_bit_cast(bf16x8,
                    *reinterpret_cast<const u32x4*>(qe_g + (nf * 16 + c16) * 64 + ks * 32 + g * 8));
                qacc[nf] = __builtin_amdgcn_mfma_f32_16x16x32_bf16(qf[ks], bfr, qacc[nf], 0, 0, 0);
            }
        }
#pragma unroll
        for (int nf = 0; nf < 8; ++nf)
#pragma unroll
            for (int r = 0; r < 4; ++r)
                qp[(w * 16 + g * 4 + r) * 128 + nf * 16 + c16] = f2bf(qacc[nf][r]);
    }
    // loop-invariant far-tile qp columns (wave-private LDS)
    f32x4 qp0v, qp126v;
#pragma unroll
    for (int r = 0; r < 4; ++r) {
        qp0v[r]   = 0.125f * bf2f(qp[(w * 16 + g * 4 + r) * 128 + 0]);
        qp126v[r] = 0.125f * bf2f(qp[(w * 16 + g * 4 + r) * 128 + 126]);
    }

    write_tile();                            // waits tile-0 vmcnt
    __syncthreads();

    float peR[32];
#pragma unroll
    for (int k = 0; k < 32; ++k) peR[k] = 0.f;
    float lreg = 0.f, acc0 = 0.f, acc126 = 0.f;
    f32x4 accO[4];
#pragma unroll
    for (int i = 0; i < 4; ++i) accO[i] = f32x4{0.f, 0.f, 0.f, 0.f};

    for (int jt = 0; jt < 16; ++jt) {
        const int j0 = jt * 64;
        const int dt = it_ - jt;
        const bool nearT = (dt >= -1) && (dt <= 1);

        if (jt < 15) load_tile(j0 + 64);     // prefetch next tile (async)

        // S = Q K^T from LDS
        f32x4 sacc[4];
#pragma unroll
        for (int nf = 0; nf < 4; ++nf) sacc[nf] = f32x4{0.f, 0.f, 0.f, 0.f};
#pragma unroll
        for (int ks = 0; ks < 2; ++ks)
#pragma unroll
            for (int nf = 0; nf < 4; ++nf) {
                bf16x8 kf = __builtin_bit_cast(bf16x8,
                    *reinterpret_cast<const u32x4*>(&Ks[(nf * 16 + c16) * 72 + ks * 32 + g * 8]));
                sacc[nf] = __builtin_amdgcn_mfma_f32_16x16x32_bf16(qf[ks], kf, sacc[nf], 0, 0, 0);
            }

        // bias + exp + P store (Ps rows wave-private)
        if (nearT) {
            const unsigned short* kpg = k_proj + ((size_t)bn * 1024 + j0) * 128;
#pragma unroll
            for (int nf = 0; nf < 4; ++nf) {
                int j_l = nf * 16 + c16;
                float mfl = mask[b * 1024 + j0 + j_l] ? 1.f : 0.f;
#pragma unroll
                for (int r = 0; r < 4; ++r) {
                    int i_l = w * 16 + g * 4 + r;
                    int e = i_l - j_l + dt * 64 + 63;
                    e = e < 0 ? 0 : (e > 126 ? 126 : e);
                    float s = sacc[nf][r] + bf2f(kpg[j_l * 128 + e]) + bf2f(qp[i_l * 128 + e]);
                    s *= 0.125f;
                    float p = (mfl > 0.f) ? __expf(s) : 0.f;
                    Ps[i_l * 72 + j_l] = f2bf(p);
                }
            }
        } else {
            const bool hi_e = (dt >= 2);
            const unsigned short* kep = kp_edge + (hi_e ? 65536 : 0) + (size_t)bn * 1024 + j0;
#pragma unroll
            for (int nf = 0; nf < 4; ++nf) {
                int j_l = nf * 16 + c16;
                float kv = 0.125f * bf2f(kep[j_l]);
                float mfl = mask[b * 1024 + j0 + j_l] ? 1.f : 0.f;
#pragma unroll
                for (int r = 0; r < 4; ++r) {
                    float s = sacc[nf][r] * 0.125f + kv + (hi_e ? qp126v[r] : qp0v[r]);
                    float p = (mfl > 0.f) ? __expf(s) : 0.f;
                    Ps[(w * 16 + g * 4 + r) * 72 + j_l] = f2bf(p);
                }
            }
        }

        // O += P @ V from LDS (P rows wave-private)
#pragma unroll
        for (int ks = 0; ks < 2; ++ks) {
            bf16x8 pf = __builtin_bit_cast(bf16x8,
                *reinterpret_cast<const u32x4*>(&Ps[(w * 16 + c16) * 72 + ks * 32 + g * 8]));
#pragma unroll
            for (int nf2 = 0; nf2 < 4; ++nf2) {
                bf16x8 vf = __builtin_bit_cast(bf16x8,
                    *reinterpret_cast<const u32x4*>(&Vt[(nf2 * 16 + c16) * 72 + ks * 32 + g * 8]));
                accO[nf2] = __builtin_amdgcn_mfma_f32_16x16x32_bf16(pf, vf, accO[nf2], 0, 0, 0);
            }
        }

        // ---- pe histogram (register bins) ----
        {
            bf16x8 s0 = __builtin_bit_cast(bf16x8,
                *reinterpret_cast<const u32x4*>(&Ps[il * 72 + part * 16]));
            bf16x8 s1 = __builtin_bit_cast(bf16x8,
                *reinterpret_cast<const u32x4*>(&Ps[il * 72 + part * 16 + 8]));
            float v[16];
#pragma unroll
            for (int m = 0; m < 8; ++m) { v[m] = (float)s0[m]; v[8 + m] = (float)s1[m]; }
            float rs = 0.f;
#pragma unroll
            for (int m = 0; m < 16; ++m) rs += v[m];
            rs += __shfl_xor(rs, 1);
            rs += __shfl_xor(rs, 2);
            lreg += rs;

            if (dt >= 2) {
                acc126 += rs;
            } else if (dt <= -2) {
                acc0 += rs;
            } else {
                const int base = il + dt * 64 + 63;   // jl for bin e is base-e
                float b0 = 0.f, b126 = 0.f;
#pragma unroll
                for (int m = 0; m < 16; ++m) {
                    int jl = part * 16 + m;
                    if (jl >= base) b0 += v[m];
                    if (jl <= base - 126) b126 += v[m];
                }
                b0 += __shfl_xor(b0, 1);     b0 += __shfl_xor(b0, 2);
                b126 += __shfl_xor(b126, 1); b126 += __shfl_xor(b126, 2);
                if (part == 0) peR[0] += b0;
                if (part == 3) peR[30] += b126;
#pragma unroll
                for (int k = 0; k < 32; ++k) {
                    int e = part * 32 + k;
                    int jl = base - e;
                    if (e >= 1 && e <= 125 && jl >= 0 && jl < 64)
                        peR[k] += bf2f(Ps[il * 72 + jl]);
                }
            }
        }
        __syncthreads();                     // all waves done reading Ks/Vt
        if (jt < 15) {
            write_tile();                    // waits prefetch vmcnt (landed)
            __syncthreads();                 // next tile visible
        }
    }

    if (part == 0) peR[0] += acc0;
    if (part == 3) peR[30] += acc126;

    // ---- end phase: overlay veT/peB/lrow on dead Ks/Vt/Ps/qp ----
#pragma unroll
    for (int c = 0; c < 4; ++c) {
        int chunk = tid + c * 256;           // 1024 chunks of 8 elems = 64x128
        int h = chunk >> 4, col = (chunk & 15) * 8;
        u32x4 vv = *reinterpret_cast<const u32x4*>(ve_t + h * 128 + col);
        *reinterpret_cast<u32x4*>(&veT[h * 136 + col]) = vv;
    }
#pragma unroll
    for (int kk = 0; kk < 4; ++kk) {         // pe spill as bf16
        bf16x8 pk;
#pragma unroll
        for (int e2 = 0; e2 < 8; ++e2) pk[e2] = (__bf16)peR[kk * 8 + e2];
        *reinterpret_cast<u32x4*>(&peB[il * 136 + part * 32 + kk * 8]) =
            __builtin_bit_cast(u32x4, pk);
    }
    if (part == 0) lrow[il] = lreg;
    __syncthreads();

    // O += pe @ veT   (K = 128; col 127 zero on both sides)
#pragma unroll
    for (int ks = 0; ks < 4; ++ks) {
        bf16x8 pf = __builtin_bit_cast(bf16x8,
            *reinterpret_cast<const u32x4*>(&peB[(w * 16 + c16) * 136 + ks * 32 + g * 8]));
#pragma unroll
        for (int nf2 = 0; nf2 < 4; ++nf2) {
            bf16x8 vf = __builtin_bit_cast(bf16x8,
                *reinterpret_cast<const u32x4*>(&veT[(nf2 * 16 + c16) * 136 + ks * 32 + g * 8]));
            accO[nf2] = __builtin_amdgcn_mfma_f32_16x16x32_bf16(pf, vf, accO[nf2], 0, 0, 0);
        }
    }

    // epilogue: attn_out[b, i, n, h] = O / l
#pragma unroll
    for (int nf2 = 0; nf2 < 4; ++nf2) {
#pragma unroll
        for (int r = 0; r < 4; ++r) {
            int i_l = w * 16 + g * 4 + r;
            int h = nf2 * 16 + c16;
            float vv = accO[nf2][r] / lrow[i_l];
            attn_out[(((size_t)b * 1024 + i0 + i_l) * 16 + (bn & 15)) * 64 + h] = f2bf(vv);
        }
    }
}

// ---------------------------------------------------------------------------
extern "C" void kernel_launch(void* const* d_in, const int* in_sizes, int n_in,
                              void* d_out, int out_size, void* d_ws, size_t ws_size,
                              hipStream_t stream)
{
    const float* x  = (const float*)d_in[0];
    const int* mask = (const int*)d_in[1];
    const float* wq = (const float*)d_in[2];
    const float* wk = (const float*)d_in[3];
    const float* wv = (const float*)d_in[4];
    const float* wo = (const float*)d_in[5];
    const float* qe = (const float*)d_in[6];
    const float* ke = (const float*)d_in[7];
    const float* ve = (const float*)d_in[8];

    char* ws = (char*)d_ws;
    size_t off = 0;
    auto carve = [&](size_t bytes) -> char* {
        char* p = ws + off;
        off += (bytes + 255) & ~(size_t)255;
        return p;
    };
    unsigned short* x_bf    = (unsigned short*)carve(4096ull * 1024 * 2);   //  8 MB
    unsigned short* wqkv_bt = (unsigned short*)carve(3072ull * 1024 * 2);   //  6 MB
    unsigned short* wo_bt   = (unsigned short*)carve(1024ull * 1024 * 2);   //  2 MB
    unsigned short* qe_bf   = (unsigned short*)carve(128ull * 64 * 2);
    unsigned short* ke_bf   = (unsigned short*)carve(128ull * 64 * 2);
    unsigned short* ve_t    = (unsigned short*)carve(64ull * 128 * 2);
    unsigned short* q_buf   = (unsigned short*)carve(65536ull * 64 * 2);    //  8 MB
    unsigned short* k_buf   = (unsigned short*)carve(65536ull * 64 * 2);    //  8 MB
    unsigned short* v_t     = (unsigned short*)carve(65536ull * 64 * 2);    //  8 MB
    unsigned short* k_proj  = (unsigned short*)carve(65536ull * 128 * 2);   // 16 MB
    unsigned short* kp_edge = (unsigned short*)carve(2ull * 65536 * 2);     // 256 KB
    unsigned short* attn_o  = (unsigned short*)carve(4096ull * 1024 * 2);   //  8 MB
    (void)ws_size; (void)in_sizes; (void)n_in; (void)out_size;

    convert_kernel<<<2048, 256, 0, stream>>>(x, wq, wk, wv, wo, qe, ke, ve,
                                             x_bf, wqkv_bt, wo_bt, qe_bf, ke_bf, ve_t);

    // QKV: [4096,1024] @ [1024,3072]; v written transposed
    gemm_bt_kernel<0><<<dim3(24, 32), 256, 0, stream>>>(
        x_bf, wqkv_bt, 1024, 1024, 1024, q_buf, k_buf, v_t, 0);

    // k_proj: [65536,64] @ [64,128(127)] (+ edge cols)
    gemm_bt_kernel<1><<<dim3(1, 512), 256, 0, stream>>>(
        k_buf, ke_bf, 64, 64, 64, k_proj, kp_edge, nullptr, 128);

    // fused attention (reg-split prefetch pipeline, XCD-grouped swizzle)
    hipFuncSetAttribute((const void*)attn_kernel,
                        hipFuncAttributeMaxDynamicSharedMemorySize, ATTN_LDS_BYTES);
    attn_kernel<<<1024, 256, ATTN_LDS_BYTES, stream>>>(
        q_buf, k_buf, v_t, qe_bf, k_proj, kp_edge, ve_t, mask, attn_o);

    // output projection: [4096,1024] @ [1024,1024] -> fp32 d_out
    gemm_bt_kernel<2><<<dim3(8, 32), 256, 0, stream>>>(
        attn_o, wo_bt, 1024, 1024, 1024, d_out, nullptr, nullptr, 1024);
}

// Round 8
// 227.308 us; speedup vs baseline: 1.3237x; 1.2845x over previous
//
#include <hip/hip_runtime.h>

// ---------------------------------------------------------------------------
// MultiHeadAttention with clipped relative-position embeddings (q/k/v-side).
// B=4, L=1024, D=1024, N=16, H=64, E=64 (127 distinct distances).
//
// Pipeline:
//   0. convert_kernel : fp32->bf16 x; weights -> k-contiguous B^T layouts;
//                       v_emb -> transposed bf16 [64][128]
//   1. gemm<0>        : QKV [4096,1024]@[1024,3072]; q/k [B,N,L,H], v ->
//                       v_t [B,N,H,L]. m97 staging (global_load_lds x16B).
//   2. gemm<1> x2     : q_proj/k_proj = q/k @ embed^T; k_proj emits kp_edge
//   3. attn_kernel    : 512-thread blocks (8 waves), QBLK=128, KVBLK=64.
//                       grid 512 = 2 blocks/CU resident (16 waves/CU).
//                       Shared stride-72 K/V^T LDS tiles + kp tile in LDS
//                       for the 4 near-union tiles (k-side gather from LDS;
//                       q-side gather from global is lane-contiguous).
//                       Far tiles rank-1 bias. Register pe bins, predicated
//                       clipped-bin sums. 2 barriers/tile.
//   4. gemm<2>        : attn_out [4096,1024] @ w_o^T -> d_out fp32
// ---------------------------------------------------------------------------

typedef __bf16 bf16x8 __attribute__((ext_vector_type(8)));
typedef float f32x4 __attribute__((ext_vector_type(4)));
typedef unsigned int u32x4 __attribute__((ext_vector_type(4)));

__device__ __forceinline__ unsigned short f2bf(float f) {
    unsigned int u = __builtin_bit_cast(unsigned int, f);
    u += 0x7fffu + ((u >> 16) & 1u);          // RNE
    return (unsigned short)(u >> 16);
}
__device__ __forceinline__ float bf2f(unsigned short s) {
    unsigned int u = ((unsigned int)s) << 16;
    return __builtin_bit_cast(float, u);
}

// async global->LDS, 16 bytes per lane; LDS dest must be wave-uniform base
__device__ __forceinline__ void gl2lds16(const unsigned short* g, unsigned short* l) {
    __builtin_amdgcn_global_load_lds(
        (const __attribute__((address_space(1))) unsigned int*)g,
        (__attribute__((address_space(3))) unsigned int*)l, 16, 0, 0);
}

// ---------------------------------------------------------------------------
// Convert / relayout kernel.
// ---------------------------------------------------------------------------
__global__ void convert_kernel(const float* __restrict__ x,
                               const float* __restrict__ wq,
                               const float* __restrict__ wk,
                               const float* __restrict__ wv,
                               const float* __restrict__ wo,
                               const float* __restrict__ qe,
                               const float* __restrict__ ke,
                               const float* __restrict__ ve,
                               unsigned short* __restrict__ x_bf,
                               unsigned short* __restrict__ wqkv_bt,
                               unsigned short* __restrict__ wo_bt,
                               unsigned short* __restrict__ qe_bf,
                               unsigned short* __restrict__ ke_bf,
                               unsigned short* __restrict__ ve_t)
{
    const size_t R0 = 4u * 1024 * 1024;
    const size_t R1 = R0 + 3u * 1024 * 1024;
    const size_t R2 = R1 + 1024u * 1024;
    const size_t R3 = R2 + 8192;
    const size_t R4 = R3 + 8192;
    const size_t R5 = R4 + 8192;
    size_t stride = (size_t)gridDim.x * blockDim.x;
    for (size_t i = (size_t)blockIdx.x * blockDim.x + threadIdx.x; i < R5; i += stride) {
        if (i < R0) {
            x_bf[i] = f2bf(x[i]);
        } else if (i < R1) {
            size_t j = i - R0;
            int which = (int)(j >> 20);
            int rem = (int)(j & 0xFFFFF);
            int n = rem >> 16, d = (rem >> 6) & 1023, h = rem & 63;
            const float* w = which == 0 ? wq : which == 1 ? wk : wv;
            wqkv_bt[(size_t)(which * 1024 + n * 64 + h) * 1024 + d] = f2bf(w[rem]);
        } else if (i < R2) {
            int rem = (int)(i - R1);
            int n = rem >> 16, h = (rem >> 10) & 63, m = rem & 1023;
            wo_bt[(size_t)m * 1024 + n * 64 + h] = f2bf(wo[rem]);
        } else if (i < R3) {
            int idx = (int)(i - R2);
            int e = idx >> 6;
            qe_bf[idx] = (e < 127) ? f2bf(qe[idx]) : 0;
        } else if (i < R4) {
            int idx = (int)(i - R3);
            int e = idx >> 6;
            ke_bf[idx] = (e < 127) ? f2bf(ke[idx]) : 0;
        } else {
            int idx = (int)(i - R4);          // ve transposed: [h=64][e=128]
            int h = idx >> 7, e = idx & 127;
            ve_t[idx] = (e < 127) ? f2bf(ve[e * 64 + h]) : 0;
        }
    }
}

// ---------------------------------------------------------------------------
// 128x128-tile bf16 GEMM, C = A @ Bt^T, m97 staging (global_load_lds x16B,
// linear [128][64] LDS). All row counts multiples of 128 (embed padded).
// MODE 0: scatter -> q/k [B,N,L,H]; v transposed [B,N,H,L]
// MODE 1: bf16 row-major C0; C1 != null: cols 0/126 -> kp_edge[2][65536]
// MODE 2: fp32 row-major C0
// ---------------------------------------------------------------------------
template<int MODE>
__global__ __launch_bounds__(256) void gemm_bt_kernel(
    const unsigned short* __restrict__ A,
    const unsigned short* __restrict__ Bt,
    int K, int lda, int ldb,
    void* __restrict__ C0, void* __restrict__ C1, void* __restrict__ C2,
    int ldc)
{
    __shared__ unsigned short As[128 * 64];
    __shared__ unsigned short Bs[128 * 64];
    const int m0 = blockIdx.y * 128;
    const int n0 = blockIdx.x * 128;
    const int tid = threadIdx.x;
    const int lane = tid & 63;
    const int w = tid >> 6;
    const int wr = w >> 1, wc = w & 1;
    const int g = lane >> 4, c16 = lane & 15;

    f32x4 acc[4][4];
#pragma unroll
    for (int i = 0; i < 4; ++i)
#pragma unroll
        for (int j = 0; j < 4; ++j) acc[i][j] = f32x4{0.f, 0.f, 0.f, 0.f};

    for (int kt = 0; kt < K; kt += 64) {
#pragma unroll
        for (int c = 0; c < 4; ++c) {
            int chunk = c * 256 + tid;           // 1024 chunks of 16B
            int row = chunk >> 3, col = (chunk & 7) * 8;
            unsigned short* ldsA = &As[(c * 256 + w * 64) * 8];   // wave-uniform
            unsigned short* ldsB = &Bs[(c * 256 + w * 64) * 8];
            gl2lds16(A  + (size_t)(m0 + row) * lda + kt + col, ldsA);
            gl2lds16(Bt + (size_t)(n0 + row) * ldb + kt + col, ldsB);
        }
        __syncthreads();
#pragma unroll
        for (int ks = 0; ks < 2; ++ks) {
            bf16x8 af[4], bfr[4];
#pragma unroll
            for (int mi = 0; mi < 4; ++mi)
                af[mi] = __builtin_bit_cast(bf16x8,
                    *reinterpret_cast<const u32x4*>(&As[(wr * 64 + mi * 16 + c16) * 64 + ks * 32 + g * 8]));
#pragma unroll
            for (int ni = 0; ni < 4; ++ni)
                bfr[ni] = __builtin_bit_cast(bf16x8,
                    *reinterpret_cast<const u32x4*>(&Bs[(wc * 64 + ni * 16 + c16) * 64 + ks * 32 + g * 8]));
#pragma unroll
            for (int mi = 0; mi < 4; ++mi)
#pragma unroll
                for (int ni = 0; ni < 4; ++ni)
                    acc[mi][ni] = __builtin_amdgcn_mfma_f32_16x16x32_bf16(af[mi], bfr[ni], acc[mi][ni], 0, 0, 0);
        }
        __syncthreads();
    }

#pragma unroll
    for (int mi = 0; mi < 4; ++mi) {
#pragma unroll
        for (int ni = 0; ni < 4; ++ni) {
#pragma unroll
            for (int r = 0; r < 4; ++r) {
                int m = m0 + wr * 64 + mi * 16 + g * 4 + r;
                int c = n0 + wc * 64 + ni * 16 + c16;
                float v = acc[mi][ni][r];
                if (MODE == 0) {
                    int b = m >> 10, l = m & 1023;
                    int which = c >> 10, n = (c >> 6) & 15, h = c & 63;
                    if (which == 2) {
                        ((unsigned short*)C2)[(((size_t)b * 16 + n) * 64 + h) * 1024 + l] = f2bf(v);
                    } else {
                        unsigned short* dst = (unsigned short*)(which == 0 ? C0 : C1);
                        dst[(((size_t)b * 16 + n) * 1024 + l) * 64 + h] = f2bf(v);
                    }
                } else if (MODE == 1) {
                    ((unsigned short*)C0)[(size_t)m * ldc + c] = f2bf(v);
                    if (C1 && (c == 0 || c == 126))
                        ((unsigned short*)C1)[(size_t)(c ? 65536 : 0) + m] = f2bf(v);
                } else {
                    ((float*)C0)[(size_t)m * ldc + c] = v;
                }
            }
        }
    }
}

// ---------------------------------------------------------------------------
// Fused attention. 512 threads (8 waves), QBLK=128, KVBLK=64.
// Grid 512 (1D): bn = id & 63 (XCD-local group), ib = id >> 6, i0 = ib*128.
// LDS: Ks[64][72]@0, Vt[64][72]@9216, Ps[128][72]@18432, kp[64][136]@36864,
//      mj[64]f32@54272, kpej[64]f32@54528 -> 54784 B.
// End overlay: veT[64][136]@0, peB[128][136]@17408, lrow[128]@52224.
// ---------------------------------------------------------------------------
#define ATTN_LDS_BYTES 54784

__global__ __launch_bounds__(512, 4) void attn_kernel(
    const unsigned short* __restrict__ q_buf,   // [B,N,L,H] bf16
    const unsigned short* __restrict__ k_buf,   // [B,N,L,H] bf16
    const unsigned short* __restrict__ v_t,     // [B,N,H,L] bf16
    const unsigned short* __restrict__ q_proj,  // [B,N,L,128] bf16
    const unsigned short* __restrict__ k_proj,  // [B,N,L,128] bf16
    const unsigned short* __restrict__ kp_edge, // [2][65536] bf16 (e=0,126)
    const unsigned short* __restrict__ ve_t,    // [64][128] bf16 (col 127 = 0)
    const int* __restrict__ mask,               // [B,1024]
    unsigned short* __restrict__ attn_out)      // [B,L,N,H] bf16
{
    extern __shared__ char smem[];
    unsigned short* Ks = (unsigned short*)smem;            // [64][72]
    unsigned short* Vt = (unsigned short*)(smem + 9216);   // [64][72]
    unsigned short* Ps = (unsigned short*)(smem + 18432);  // [128][72]
    unsigned short* kp = (unsigned short*)(smem + 36864);  // [64][136]
    float* mj   = (float*)(smem + 54272);                  // [64]
    float* kpej = (float*)(smem + 54528);                  // [64]
    unsigned short* veT = (unsigned short*)smem;           // [64][136] overlay
    unsigned short* peB = (unsigned short*)(smem + 17408); // [128][136] overlay
    float* lrow = (float*)(smem + 52224);                  // [128]

    const int id = blockIdx.x;
    const int bn = id & 63;                  // = b*16 + n (same XCD per group)
    const int ib = id >> 6;                  // i-block, 128 rows
    const int b = bn >> 4;
    const int i0 = ib * 128;
    const int tid = threadIdx.x;
    const int lane = tid & 63;
    const int w = tid >> 6;                  // wave 0..7, owns rows [w*16,w*16+16)
    const int g = lane >> 4, c16 = lane & 15;
    const int il = tid >> 2;                 // histogram row 0..127
    const int part = tid & 3;                // bins [part*32, part*32+32)

    // K/V staging geometry: 512 chunks of 16B per [64][64] tile, 1/thread
    const int sr = tid >> 3, sc = (tid & 7) * 8;

    // Q fragments (A-row = c16), k-slot = ks*32 + 8g + slot
    bf16x8 qf[2];
    {
        const unsigned short* qrow = q_buf + ((size_t)bn * 1024 + i0 + w * 16 + c16) * 64;
        qf[0] = __builtin_bit_cast(bf16x8, *reinterpret_cast<const u32x4*>(qrow + g * 8));
        qf[1] = __builtin_bit_cast(bf16x8, *reinterpret_cast<const u32x4*>(qrow + 32 + g * 8));
    }
    // loop-invariant far-tile qp edge columns (global, 8 scalar loads)
    f32x4 qp0v, qp126v;
#pragma unroll
    for (int r = 0; r < 4; ++r) {
        size_t row = (size_t)bn * 1024 + i0 + w * 16 + g * 4 + r;
        qp0v[r]   = 0.125f * bf2f(q_proj[row * 128 + 0]);
        qp126v[r] = 0.125f * bf2f(q_proj[row * 128 + 126]);
    }

    float peR[32];
#pragma unroll
    for (int k = 0; k < 32; ++k) peR[k] = 0.f;
    float lreg = 0.f, acc0 = 0.f, acc126 = 0.f;
    f32x4 accO[4];
#pragma unroll
    for (int i = 0; i < 4; ++i) accO[i] = f32x4{0.f, 0.f, 0.f, 0.f};

    const int jlo = 2 * ib - 1, jhi = 2 * ib + 2;   // kp-staging window

    for (int jt = 0; jt < 16; ++jt) {
        const int j0 = jt * 64;
        const bool need_kp = (jt >= jlo) && (jt <= jhi);

        // ---- stage K, V^T (+ kp when near-union), mask, far edge bias ----
        {
            u32x4 kv = *reinterpret_cast<const u32x4*>(k_buf + ((size_t)bn * 1024 + j0 + sr) * 64 + sc);
            u32x4 vv = *reinterpret_cast<const u32x4*>(v_t + ((size_t)bn * 64 + sr) * 1024 + j0 + sc);
            *reinterpret_cast<u32x4*>(&Ks[sr * 72 + sc]) = kv;
            *reinterpret_cast<u32x4*>(&Vt[sr * 72 + sc]) = vv;
        }
        if (need_kp) {
#pragma unroll
            for (int c = 0; c < 2; ++c) {
                int chunk = tid + c * 512;        // 1024 chunks of 8 elems
                int row = chunk >> 4, col = (chunk & 15) * 8;
                u32x4 v = *reinterpret_cast<const u32x4*>(k_proj + ((size_t)bn * 1024 + j0 + row) * 128 + col);
                *reinterpret_cast<u32x4*>(&kp[row * 136 + col]) = v;
            }
        }
        if (tid < 64) {
            mj[tid] = mask[b * 1024 + j0 + tid] ? 1.f : 0.f;
            // far-plane: tiles left of the i-block use e=126, right use e=0
            kpej[tid] = 0.125f * bf2f(kp_edge[(size_t)(jt < 2 * ib ? 65536 : 0) + bn * 1024 + j0 + tid]);
        }
        __syncthreads();

        // ---- S = Q K^T ----
        f32x4 sacc[4];
#pragma unroll
        for (int nf = 0; nf < 4; ++nf) sacc[nf] = f32x4{0.f, 0.f, 0.f, 0.f};
#pragma unroll
        for (int ks = 0; ks < 2; ++ks)
#pragma unroll
            for (int nf = 0; nf < 4; ++nf) {
                bf16x8 kf = __builtin_bit_cast(bf16x8,
                    *reinterpret_cast<const u32x4*>(&Ks[(nf * 16 + c16) * 72 + ks * 32 + g * 8]));
                sacc[nf] = __builtin_amdgcn_mfma_f32_16x16x32_bf16(qf[ks], kf, sacc[nf], 0, 0, 0);
            }

        // ---- bias + exp + P store (wave-uniform near/far decision) ----
        const int dw = i0 + w * 16 - j0;
        if (dw < 126 && dw > -78) {
            // near: k-side gather from LDS kp, q-side gather from global
            const int d0 = i0 - j0 + 63;
            const unsigned short* qpg = q_proj + ((size_t)bn * 1024 + i0) * 128;
#pragma unroll
            for (int nf = 0; nf < 4; ++nf) {
                int j_l = nf * 16 + c16;
                float mfl = mj[j_l];
#pragma unroll
                for (int r = 0; r < 4; ++r) {
                    int i_l = w * 16 + g * 4 + r;
                    int e = d0 + i_l - j_l;
                    e = e < 0 ? 0 : (e > 126 ? 126 : e);
                    float s = sacc[nf][r] + bf2f(kp[j_l * 136 + e]) + bf2f(qpg[i_l * 128 + e]);
                    s *= 0.125f;
                    float p = (mfl > 0.f) ? __expf(s) : 0.f;
                    Ps[i_l * 72 + j_l] = f2bf(p);
                }
            }
        } else {
            const f32x4 qpc = (dw >= 126) ? qp126v : qp0v;
#pragma unroll
            for (int nf = 0; nf < 4; ++nf) {
                int j_l = nf * 16 + c16;
                float kv = kpej[j_l];
                float mfl = mj[j_l];
#pragma unroll
                for (int r = 0; r < 4; ++r) {
                    float s = sacc[nf][r] * 0.125f + kv + qpc[r];
                    float p = (mfl > 0.f) ? __expf(s) : 0.f;
                    Ps[(w * 16 + g * 4 + r) * 72 + j_l] = f2bf(p);
                }
            }
        }

        // ---- O += P @ V (Ps rows wave-private; lgkmcnt orders RAW) ----
#pragma unroll
        for (int ks = 0; ks < 2; ++ks) {
            bf16x8 pf = __builtin_bit_cast(bf16x8,
                *reinterpret_cast<const u32x4*>(&Ps[(w * 16 + c16) * 72 + ks * 32 + g * 8]));
#pragma unroll
            for (int nf2 = 0; nf2 < 4; ++nf2) {
                bf16x8 vf = __builtin_bit_cast(bf16x8,
                    *reinterpret_cast<const u32x4*>(&Vt[(nf2 * 16 + c16) * 72 + ks * 32 + g * 8]));
                accO[nf2] = __builtin_amdgcn_mfma_f32_16x16x32_bf16(pf, vf, accO[nf2], 0, 0, 0);
            }
        }

        // ---- pe histogram (register bins; per-row near/far) ----
        {
            bf16x8 s0 = __builtin_bit_cast(bf16x8,
                *reinterpret_cast<const u32x4*>(&Ps[il * 72 + part * 16]));
            bf16x8 s1 = __builtin_bit_cast(bf16x8,
                *reinterpret_cast<const u32x4*>(&Ps[il * 72 + part * 16 + 8]));
            float v[16];
#pragma unroll
            for (int m = 0; m < 8; ++m) { v[m] = (float)s0[m]; v[8 + m] = (float)s1[m]; }
            float rs = 0.f;
#pragma unroll
            for (int m = 0; m < 16; ++m) rs += v[m];
            rs += __shfl_xor(rs, 1);
            rs += __shfl_xor(rs, 2);
            lreg += rs;

            const int base = i0 + il - j0 + 63;   // jl for bin e is base - e
            if (base >= 189) {
                acc126 += rs;                     // every e >= 126
            } else if (base <= 0) {
                acc0 += rs;                       // every e <= 0
            } else {
                float b0 = 0.f, b126 = 0.f;
#pragma unroll
                for (int m = 0; m < 16; ++m) {
                    int jl = part * 16 + m;
                    if (jl >= base) b0 += v[m];
                    if (jl <= base - 126) b126 += v[m];
                }
                b0 += __shfl_xor(b0, 1);     b0 += __shfl_xor(b0, 2);
                b126 += __shfl_xor(b126, 1); b126 += __shfl_xor(b126, 2);
                if (part == 0) peR[0] += b0;
                if (part == 3) peR[30] += b126;
#pragma unroll
                for (int k = 0; k < 32; ++k) {
                    int e = part * 32 + k;
                    int jl = base - e;
                    if (e >= 1 && e <= 125 && jl >= 0 && jl < 64)
                        peR[k] += bf2f(Ps[il * 72 + jl]);
                }
            }
        }
        __syncthreads();                     // all waves done with Ks/Vt/kp
    }

    if (part == 0) peR[0] += acc0;
    if (part == 3) peR[30] += acc126;

    // ---- end phase: overlay veT/peB/lrow on dead Ks/Vt/Ps/kp ----
#pragma unroll
    for (int c = 0; c < 2; ++c) {
        int chunk = tid + c * 512;           // 1024 chunks of 8 elems = 64x128
        int h = chunk >> 4, col = (chunk & 15) * 8;
        u32x4 vv = *reinterpret_cast<const u32x4*>(ve_t + h * 128 + col);
        *reinterpret_cast<u32x4*>(&veT[h * 136 + col]) = vv;
    }
#pragma unroll
    for (int kk = 0; kk < 4; ++kk) {         // pe spill as bf16
        bf16x8 pk;
#pragma unroll
        for (int e2 = 0; e2 < 8; ++e2) pk[e2] = (__bf16)peR[kk * 8 + e2];
        *reinterpret_cast<u32x4*>(&peB[il * 136 + part * 32 + kk * 8]) =
            __builtin_bit_cast(u32x4, pk);
    }
    if (part == 0) lrow[il] = lreg;
    __syncthreads();

    // O += pe @ veT   (K = 128; col 127 zero on both sides)
#pragma unroll
    for (int ks = 0; ks < 4; ++ks) {
        bf16x8 pf = __builtin_bit_cast(bf16x8,
            *reinterpret_cast<const u32x4*>(&peB[(w * 16 + c16) * 136 + ks * 32 + g * 8]));
#pragma unroll
        for (int nf2 = 0; nf2 < 4; ++nf2) {
            bf16x8 vf = __builtin_bit_cast(bf16x8,
                *reinterpret_cast<const u32x4*>(&veT[(nf2 * 16 + c16) * 136 + ks * 32 + g * 8]));
            accO[nf2] = __builtin_amdgcn_mfma_f32_16x16x32_bf16(pf, vf, accO[nf2], 0, 0, 0);
        }
    }

    // epilogue: attn_out[b, i, n, h] = O / l
#pragma unroll
    for (int nf2 = 0; nf2 < 4; ++nf2) {
#pragma unroll
        for (int r = 0; r < 4; ++r) {
            int i_l = w * 16 + g * 4 + r;
            int h = nf2 * 16 + c16;
            float vv = accO[nf2][r] / lrow[i_l];
            attn_out[(((size_t)b * 1024 + i0 + i_l) * 16 + (bn & 15)) * 64 + h] = f2bf(vv);
        }
    }
}

// ---------------------------------------------------------------------------
extern "C" void kernel_launch(void* const* d_in, const int* in_sizes, int n_in,
                              void* d_out, int out_size, void* d_ws, size_t ws_size,
                              hipStream_t stream)
{
    const float* x  = (const float*)d_in[0];
    const int* mask = (const int*)d_in[1];
    const float* wq = (const float*)d_in[2];
    const float* wk = (const float*)d_in[3];
    const float* wv = (const float*)d_in[4];
    const float* wo = (const float*)d_in[5];
    const float* qe = (const float*)d_in[6];
    const float* ke = (const float*)d_in[7];
    const float* ve = (const float*)d_in[8];

    char* ws = (char*)d_ws;
    size_t off = 0;
    auto carve = [&](size_t bytes) -> char* {
        char* p = ws + off;
        off += (bytes + 255) & ~(size_t)255;
        return p;
    };
    unsigned short* x_bf    = (unsigned short*)carve(4096ull * 1024 * 2);   //  8 MB
    unsigned short* wqkv_bt = (unsigned short*)carve(3072ull * 1024 * 2);   //  6 MB
    unsigned short* wo_bt   = (unsigned short*)carve(1024ull * 1024 * 2);   //  2 MB
    unsigned short* qe_bf   = (unsigned short*)carve(128ull * 64 * 2);
    unsigned short* ke_bf   = (unsigned short*)carve(128ull * 64 * 2);
    unsigned short* ve_t    = (unsigned short*)carve(64ull * 128 * 2);
    unsigned short* q_buf   = (unsigned short*)carve(65536ull * 64 * 2);    //  8 MB
    unsigned short* k_buf   = (unsigned short*)carve(65536ull * 64 * 2);    //  8 MB
    unsigned short* v_t     = (unsigned short*)carve(65536ull * 64 * 2);    //  8 MB
    unsigned short* q_proj  = (unsigned short*)carve(65536ull * 128 * 2);   // 16 MB
    unsigned short* k_proj  = (unsigned short*)carve(65536ull * 128 * 2);   // 16 MB
    unsigned short* kp_edge = (unsigned short*)carve(2ull * 65536 * 2);     // 256 KB
    unsigned short* attn_o  = (unsigned short*)carve(4096ull * 1024 * 2);   //  8 MB
    (void)ws_size; (void)in_sizes; (void)n_in; (void)out_size;

    convert_kernel<<<2048, 256, 0, stream>>>(x, wq, wk, wv, wo, qe, ke, ve,
                                             x_bf, wqkv_bt, wo_bt, qe_bf, ke_bf, ve_t);

    // QKV: [4096,1024] @ [1024,3072]; v written transposed
    gemm_bt_kernel<0><<<dim3(24, 32), 256, 0, stream>>>(
        x_bf, wqkv_bt, 1024, 1024, 1024, q_buf, k_buf, v_t, 0);

    // q_proj / k_proj: [65536,64] @ [64,128(127)]
    gemm_bt_kernel<1><<<dim3(1, 512), 256, 0, stream>>>(
        q_buf, qe_bf, 64, 64, 64, q_proj, nullptr, nullptr, 128);
    gemm_bt_kernel<1><<<dim3(1, 512), 256, 0, stream>>>(
        k_buf, ke_bf, 64, 64, 64, k_proj, kp_edge, nullptr, 128);

    // fused attention (8-wave blocks, 2 resident/CU, XCD-grouped swizzle)
    hipFuncSetAttribute((const void*)attn_kernel,
                        hipFuncAttributeMaxDynamicSharedMemorySize, ATTN_LDS_BYTES);
    attn_kernel<<<512, 512, ATTN_LDS_BYTES, stream>>>(
        q_buf, k_buf, v_t, q_proj, k_proj, kp_edge, ve_t, mask, attn_o);

    // output projection: [4096,1024] @ [1024,1024] -> fp32 d_out
    gemm_bt_kernel<2><<<dim3(8, 32), 256, 0, stream>>>(
        attn_o, wo_bt, 1024, 1024, 1024, d_out, nullptr, nullptr, 1024);
}